// Round 4
// baseline (166.286 us; speedup 1.0000x reference)
//
#include <hip/hip_runtime.h>
#include <hip/hip_bf16.h>

#define NN 1500
#define GIN 32
#define GOUT 8
#define HID 128
#define CAP 192           // max nnz/row kept; mean ~60, sigma ~7.6 -> 17 sigma headroom

typedef float v2f __attribute__((ext_vector_type(2)));

// ---------------------------------------------------------------------------
// Fused: compact combined adjacency row (geo+sem > 0) into LDS, write CSR for
// layers 2-3, and compute GAT layer 1 attention for this row in one kernel.
// One block (256 thr) per row.
// ---------------------------------------------------------------------------
__global__ void gat_first(const float* __restrict__ geo,
                          const float* __restrict__ sem,
                          const float* __restrict__ feat,   // NN x 32
                          const float* __restrict__ W0,     // 32 x 8
                          const float* __restrict__ a0,     // 16
                          int* __restrict__ csr_idx,
                          float* __restrict__ csr_val,
                          int* __restrict__ csr_cnt,
                          float* __restrict__ enc_out) {
    const int i = blockIdx.x;
    const int t = threadIdx.x;  // 256
    __shared__ int cnt;
    __shared__ int sidx[CAP];
    __shared__ float sval[CAP];
    __shared__ float hi_s[GOUT];
    __shared__ float wsum[4][GOUT + 1];
    if (t == 0) cnt = 0;
    __syncthreads();

    const float* grow = geo + (size_t)i * NN;
    const float* srow = sem + (size_t)i * NN;
    for (int q = t; q < NN / 4; q += 256) {
        float4 g = *(const float4*)(grow + 4 * q);
        float4 s = *(const float4*)(srow + 4 * q);
        float a[4] = {g.x + s.x, g.y + s.y, g.z + s.z, g.w + s.w};
        #pragma unroll
        for (int c = 0; c < 4; ++c) {
            if (a[c] > 0.f) {
                int p = atomicAdd(&cnt, 1);
                if (p < CAP) { sidx[p] = 4 * q + c; sval[p] = a[c]; }
            }
        }
    }
    // h_i (only needed for f_src): threads 0..7
    if (t < GOUT) {
        float hv = 0.f;
        #pragma unroll 4
        for (int c = 0; c < GIN; ++c)
            hv = fmaf(feat[(size_t)i * GIN + c], W0[c * GOUT + t], hv);
        hi_s[t] = hv;
    }
    __syncthreads();

    const int c2 = cnt < CAP ? cnt : CAP;
    if (t == 0) csr_cnt[i] = c2;
    for (int p = t; p < c2; p += 256) {
        csr_idx[(size_t)i * CAP + p] = sidx[p];
        csr_val[(size_t)i * CAP + p] = sval[p];
    }
    float fsrc = 0.f;
    #pragma unroll
    for (int k = 0; k < GOUT; ++k) fsrc = fmaf(hi_s[k], a0[k], fsrc);

    // attention: one entry per thread (cnt <= 192 < 256 -> single pass)
    float den = 0.f;
    float num[GOUT] = {};
    if (t < c2) {
        int j = sidx[t];
        float a = sval[t];
        float hj[GOUT] = {};
        #pragma unroll
        for (int c4 = 0; c4 < GIN / 4; ++c4) {
            float4 e4 = *(const float4*)(feat + (size_t)j * GIN + 4 * c4);
            const float* ep = (const float*)&e4;
            #pragma unroll
            for (int c = 0; c < 4; ++c)
                #pragma unroll
                for (int k = 0; k < GOUT; ++k)
                    hj[k] = fmaf(ep[c], W0[(4 * c4 + c) * GOUT + k], hj[k]);
        }
        float fd = 0.f;
        #pragma unroll
        for (int k = 0; k < GOUT; ++k) fd = fmaf(hj[k], a0[GOUT + k], fd);
        float ev = fsrc + fd;
        ev = (ev > 0.f) ? ev : 0.2f * ev;
        ev *= a;
        float p = __expf(ev);
        den = p;
        #pragma unroll
        for (int k = 0; k < GOUT; ++k) num[k] = p * hj[k];
    }
    #pragma unroll
    for (int off = 32; off > 0; off >>= 1) {
        den += __shfl_xor(den, off, 64);
        #pragma unroll
        for (int k = 0; k < GOUT; ++k) num[k] += __shfl_xor(num[k], off, 64);
    }
    if ((t & 63) == 0) {
        wsum[t >> 6][0] = den;
        #pragma unroll
        for (int k = 0; k < GOUT; ++k) wsum[t >> 6][1 + k] = num[k];
    }
    __syncthreads();
    if (t < GOUT) {
        float L = wsum[0][0] + wsum[1][0] + wsum[2][0] + wsum[3][0];
        float v = (wsum[0][1 + t] + wsum[1][1 + t] + wsum[2][1 + t] + wsum[3][1 + t]) / L;
        enc_out[(size_t)i * GOUT + t] = (v > 0.f) ? v : (__expf(v) - 1.f);
    }
}

// ---------------------------------------------------------------------------
// GAT layers 2,3: one WAVE per row i, CSR-driven (unchanged from round 3).
// ---------------------------------------------------------------------------
template<int IN>
__global__ void gat_layer(const float* __restrict__ enc,
                          const float* __restrict__ W,     // IN x 8
                          const float* __restrict__ avec,  // 16
                          const int* __restrict__ csr_idx,
                          const float* __restrict__ csr_val,
                          const int* __restrict__ csr_cnt,
                          float* __restrict__ enc_out) {
    const int tid = threadIdx.x;            // 256 = 4 waves, 1 wave per row
    const int lane = tid & 63;
    const int i = blockIdx.x * 4 + (tid >> 6);   // 375*4 == 1500 exact

    float hv = 0.f;
    if (lane < GOUT) {
        #pragma unroll 4
        for (int c = 0; c < IN; ++c)
            hv = fmaf(enc[(size_t)i * IN + c], W[c * GOUT + lane], hv);
    }
    float hi[GOUT];
    #pragma unroll
    for (int c = 0; c < GOUT; ++c) hi[c] = __shfl(hv, c, 64);
    float fsrc = 0.f;
    #pragma unroll
    for (int c = 0; c < GOUT; ++c) fsrc = fmaf(hi[c], avec[c], fsrc);

    const int cnt = csr_cnt[i];
    float den = 0.f;
    float num[GOUT] = {};
    for (int e = lane; e < cnt; e += 64) {
        int j = csr_idx[(size_t)i * CAP + e];
        float a = csr_val[(size_t)i * CAP + e];
        float hj[GOUT] = {};
        #pragma unroll
        for (int c4 = 0; c4 < IN / 4; ++c4) {
            float4 e4 = *(const float4*)(enc + (size_t)j * IN + 4 * c4);
            const float* ep = (const float*)&e4;
            #pragma unroll
            for (int c = 0; c < 4; ++c)
                #pragma unroll
                for (int k = 0; k < GOUT; ++k)
                    hj[k] = fmaf(ep[c], W[(4 * c4 + c) * GOUT + k], hj[k]);
        }
        float fd = 0.f;
        #pragma unroll
        for (int k = 0; k < GOUT; ++k) fd = fmaf(hj[k], avec[GOUT + k], fd);
        float ev = fsrc + fd;
        ev = (ev > 0.f) ? ev : 0.2f * ev;
        ev *= a;
        float p = __expf(ev);
        den += p;
        #pragma unroll
        for (int k = 0; k < GOUT; ++k) num[k] = fmaf(p, hj[k], num[k]);
    }
    #pragma unroll
    for (int off = 32; off > 0; off >>= 1) {
        den += __shfl_xor(den, off, 64);
        #pragma unroll
        for (int k = 0; k < GOUT; ++k) num[k] += __shfl_xor(num[k], off, 64);
    }
    if (lane < GOUT) {
        float v = num[lane] / den;
        enc_out[(size_t)i * GOUT + lane] = (v > 0.f) ? v : (__expf(v) - 1.f);
    }
}

// ---------------------------------------------------------------------------
// Fused UV + pair-MLP, 96x96 tile, 6x6 register tile, k split into 2 phases
// of 64 so LDS = 2*96*68*4 = 52 KB. Grid 16x16 = 256 blocks = 1 per CU.
// LDS bytes/output = 4*(6+6)/36*128 = 170 B (vs 341 at 3x3) -> ~7.3 us LDS,
// balancing the ~7.7 us of packed VALU.
// ---------------------------------------------------------------------------
#define MT 96
#define KS 64
#define KSTR 68   // 64 + 4 pad; row base 16B-aligned (272 B); banks 4r%32 -> 2-way (free)

__global__ __launch_bounds__(256, 1) void mlp_kernel(
        const float* __restrict__ enc,
        const float* __restrict__ dist,
        const float* __restrict__ fc1w,   // 17 x 128
        const float* __restrict__ fc1b,   // 128
        const float* __restrict__ fc2w,   // 128
        const float* __restrict__ fc2b,   // 1
        float* __restrict__ out) {
    __shared__ float Us[MT * KSTR];
    __shared__ float Vs[MT * KSTR];
    __shared__ float w16s[HID];
    __shared__ float f2s[HID];

    const int tid = threadIdx.x;
    const int i0 = blockIdx.y * MT;
    const int j0 = blockIdx.x * MT;
    const int tx = tid & 15;
    const int ty = tid >> 4;

    if (tid < HID) {
        w16s[tid] = fc1w[2 * GOUT * HID + tid];
        f2s[tid] = fc2w[tid];
    }

    // distance tile: 36 scalars, persists in registers across both k-phases
    int irow[6], jcol[6];
    float d[6][6];
    #pragma unroll
    for (int ii = 0; ii < 6; ++ii) irow[ii] = i0 + ty + 16 * ii;
    #pragma unroll
    for (int jj = 0; jj < 6; ++jj) jcol[jj] = j0 + tx + 16 * jj;
    #pragma unroll
    for (int ii = 0; ii < 6; ++ii) {
        int ic = irow[ii] < NN ? irow[ii] : NN - 1;
        #pragma unroll
        for (int jj = 0; jj < 6; ++jj) {
            int jc = jcol[jj] < NN ? jcol[jj] : NN - 1;
            d[ii][jj] = dist[(size_t)ic * NN + jc];
        }
    }

    v2f acc[6][6] = {};

    #pragma unroll
    for (int ph = 0; ph < 2; ++ph) {
        const int k0 = ph * KS;
        // stage U/V for this k-phase: 2*96*16 float4-units, 12 per thread.
        // s=0..5 -> pure U, s=6..11 -> pure V (no intra-wave divergence).
        for (int u = tid; u < 2 * MT * 16; u += 256) {
            const int isU = (u < MT * 16);
            const int q = isU ? u : u - MT * 16;
            const int r = q >> 4;
            const int k4 = k0 + ((q & 15) << 2);
            int g = (isU ? i0 : j0) + r;
            if (g >= NN) g = NN - 1;
            float4 acc4;
            if (isU) acc4 = *(const float4*)(fc1b + k4);
            else acc4 = make_float4(0.f, 0.f, 0.f, 0.f);
            const float* wbase = fc1w + (isU ? 0 : GOUT) * HID + k4;
            const float* ep = enc + (size_t)g * GOUT;
            #pragma unroll
            for (int c = 0; c < GOUT; ++c) {
                float e = ep[c];
                float4 w4 = *(const float4*)(wbase + c * HID);
                acc4.x = fmaf(e, w4.x, acc4.x);
                acc4.y = fmaf(e, w4.y, acc4.y);
                acc4.z = fmaf(e, w4.z, acc4.z);
                acc4.w = fmaf(e, w4.w, acc4.w);
            }
            *(float4*)((isU ? Us : Vs) + r * KSTR + (k4 - k0)) = acc4;
        }
        __syncthreads();

        for (int k4 = 0; k4 < KS; k4 += 4) {
            float4 u4[6], v4[6];
            #pragma unroll
            for (int ii = 0; ii < 6; ++ii)
                u4[ii] = *(const float4*)(Us + (ty + 16 * ii) * KSTR + k4);
            #pragma unroll
            for (int jj = 0; jj < 6; ++jj)
                v4[jj] = *(const float4*)(Vs + (tx + 16 * jj) * KSTR + k4);
            float4 wk = *(const float4*)(w16s + k0 + k4);
            float4 fk = *(const float4*)(f2s + k0 + k4);
            const v2f* wp = (const v2f*)&wk;
            const v2f* fp = (const v2f*)&fk;
            #pragma unroll
            for (int h = 0; h < 2; ++h) {
                v2f w2 = wp[h];
                v2f f2 = fp[h];
                #pragma unroll
                for (int ii = 0; ii < 6; ++ii) {
                    v2f u2 = ((const v2f*)&u4[ii])[h];
                    #pragma unroll
                    for (int jj = 0; jj < 6; ++jj) {
                        v2f tt = u2 + ((const v2f*)&v4[jj])[h];
                        tt = tt + w2 * d[ii][jj];                 // v_pk_fma (splat d)
                        tt = __builtin_elementwise_max(tt, (v2f)0.f);
                        acc[ii][jj] = acc[ii][jj] + tt * f2;      // v_pk_fma
                    }
                }
            }
        }
        __syncthreads();
    }

    const float b2 = fc2b[0];
    #pragma unroll
    for (int ii = 0; ii < 6; ++ii) {
        if (irow[ii] >= NN) continue;
        #pragma unroll
        for (int jj = 0; jj < 6; ++jj) {
            if (jcol[jj] >= NN) continue;
            out[(size_t)irow[ii] * NN + jcol[jj]] = acc[ii][jj].x + acc[ii][jj].y + b2;
        }
    }
}

// ---------------------------------------------------------------------------
extern "C" void kernel_launch(void* const* d_in, const int* in_sizes, int n_in,
                              void* d_out, int out_size, void* d_ws, size_t ws_size,
                              hipStream_t stream) {
    const float* geo  = (const float*)d_in[0];
    const float* sem  = (const float*)d_in[1];
    const float* feat = (const float*)d_in[2];
    // d_in[3] = region_pairs: full meshgrid -> row-major (i,j); unused
    const float* dist = (const float*)d_in[4];
    const float* W0   = (const float*)d_in[5];
    const float* W1   = (const float*)d_in[6];
    const float* W2   = (const float*)d_in[7];
    const float* a0   = (const float*)d_in[8];
    const float* a1   = (const float*)d_in[9];
    const float* a2   = (const float*)d_in[10];
    const float* fc1w = (const float*)d_in[11];
    const float* fc1b = (const float*)d_in[12];
    const float* fc2w = (const float*)d_in[13];
    const float* fc2b = (const float*)d_in[14];
    float* out = (float*)d_out;

    // workspace layout (~2.5 MB)
    char* ws = (char*)d_ws;
    int*   csr_idx = (int*)ws;                         ws += sizeof(int) * NN * CAP;
    float* csr_val = (float*)ws;                       ws += sizeof(float) * NN * CAP;
    int*   csr_cnt = (int*)ws;                         ws += sizeof(int) * NN;
    float* encA    = (float*)ws;                       ws += sizeof(float) * NN * GOUT;
    float* encB    = (float*)ws;

    gat_first<<<NN, 256, 0, stream>>>(geo, sem, feat, W0, a0,
                                      csr_idx, csr_val, csr_cnt, encA);
    gat_layer<GOUT><<<NN / 4, 256, 0, stream>>>(encA, W1, a1, csr_idx, csr_val, csr_cnt, encB);
    gat_layer<GOUT><<<NN / 4, 256, 0, stream>>>(encB, W2, a2, csr_idx, csr_val, csr_cnt, encA);

    dim3 mg(16, 16);
    mlp_kernel<<<mg, 256, 0, stream>>>(encA, dist, fc1w, fc1b, fc2w, fc2b, out);
}

// Round 5
// 160.248 us; speedup vs baseline: 1.0377x; 1.0377x over previous
//
#include <hip/hip_runtime.h>
#include <hip/hip_bf16.h>

#define NN 1500
#define GIN 32
#define GOUT 8
#define HID 128
#define CAP 192           // max nnz/row kept; mean ~60, sigma ~7.6 -> 17 sigma headroom

typedef float v2f __attribute__((ext_vector_type(2)));

// ---------------------------------------------------------------------------
// Fused: compact combined adjacency row (geo+sem > 0) into LDS, write CSR for
// layers 2-3, and compute GAT layer 1 attention for this row in one kernel.
// One block (256 thr) per row.
// ---------------------------------------------------------------------------
__global__ void gat_first(const float* __restrict__ geo,
                          const float* __restrict__ sem,
                          const float* __restrict__ feat,   // NN x 32
                          const float* __restrict__ W0,     // 32 x 8
                          const float* __restrict__ a0,     // 16
                          int* __restrict__ csr_idx,
                          float* __restrict__ csr_val,
                          int* __restrict__ csr_cnt,
                          float* __restrict__ enc_out) {
    const int i = blockIdx.x;
    const int t = threadIdx.x;  // 256
    __shared__ int cnt;
    __shared__ int sidx[CAP];
    __shared__ float sval[CAP];
    __shared__ float hi_s[GOUT];
    __shared__ float wsum[4][GOUT + 1];
    if (t == 0) cnt = 0;
    __syncthreads();

    const float* grow = geo + (size_t)i * NN;
    const float* srow = sem + (size_t)i * NN;
    for (int q = t; q < NN / 4; q += 256) {
        float4 g = *(const float4*)(grow + 4 * q);
        float4 s = *(const float4*)(srow + 4 * q);
        float a[4] = {g.x + s.x, g.y + s.y, g.z + s.z, g.w + s.w};
        #pragma unroll
        for (int c = 0; c < 4; ++c) {
            if (a[c] > 0.f) {
                int p = atomicAdd(&cnt, 1);
                if (p < CAP) { sidx[p] = 4 * q + c; sval[p] = a[c]; }
            }
        }
    }
    // h_i (only needed for f_src): threads 0..7
    if (t < GOUT) {
        float hv = 0.f;
        #pragma unroll 4
        for (int c = 0; c < GIN; ++c)
            hv = fmaf(feat[(size_t)i * GIN + c], W0[c * GOUT + t], hv);
        hi_s[t] = hv;
    }
    __syncthreads();

    const int c2 = cnt < CAP ? cnt : CAP;
    if (t == 0) csr_cnt[i] = c2;
    for (int p = t; p < c2; p += 256) {
        csr_idx[(size_t)i * CAP + p] = sidx[p];
        csr_val[(size_t)i * CAP + p] = sval[p];
    }
    float fsrc = 0.f;
    #pragma unroll
    for (int k = 0; k < GOUT; ++k) fsrc = fmaf(hi_s[k], a0[k], fsrc);

    // attention: one entry per thread (cnt <= 192 < 256 -> single pass)
    float den = 0.f;
    float num[GOUT] = {};
    if (t < c2) {
        int j = sidx[t];
        float a = sval[t];
        float hj[GOUT] = {};
        #pragma unroll
        for (int c4 = 0; c4 < GIN / 4; ++c4) {
            float4 e4 = *(const float4*)(feat + (size_t)j * GIN + 4 * c4);
            const float* ep = (const float*)&e4;
            #pragma unroll
            for (int c = 0; c < 4; ++c)
                #pragma unroll
                for (int k = 0; k < GOUT; ++k)
                    hj[k] = fmaf(ep[c], W0[(4 * c4 + c) * GOUT + k], hj[k]);
        }
        float fd = 0.f;
        #pragma unroll
        for (int k = 0; k < GOUT; ++k) fd = fmaf(hj[k], a0[GOUT + k], fd);
        float ev = fsrc + fd;
        ev = (ev > 0.f) ? ev : 0.2f * ev;
        ev *= a;
        float p = __expf(ev);
        den = p;
        #pragma unroll
        for (int k = 0; k < GOUT; ++k) num[k] = p * hj[k];
    }
    #pragma unroll
    for (int off = 32; off > 0; off >>= 1) {
        den += __shfl_xor(den, off, 64);
        #pragma unroll
        for (int k = 0; k < GOUT; ++k) num[k] += __shfl_xor(num[k], off, 64);
    }
    if ((t & 63) == 0) {
        wsum[t >> 6][0] = den;
        #pragma unroll
        for (int k = 0; k < GOUT; ++k) wsum[t >> 6][1 + k] = num[k];
    }
    __syncthreads();
    if (t < GOUT) {
        float L = wsum[0][0] + wsum[1][0] + wsum[2][0] + wsum[3][0];
        float v = (wsum[0][1 + t] + wsum[1][1 + t] + wsum[2][1 + t] + wsum[3][1 + t]) / L;
        enc_out[(size_t)i * GOUT + t] = (v > 0.f) ? v : (__expf(v) - 1.f);
    }
}

// ---------------------------------------------------------------------------
// GAT layers 2,3: one WAVE per row i, CSR-driven.
// ---------------------------------------------------------------------------
template<int IN>
__global__ void gat_layer(const float* __restrict__ enc,
                          const float* __restrict__ W,     // IN x 8
                          const float* __restrict__ avec,  // 16
                          const int* __restrict__ csr_idx,
                          const float* __restrict__ csr_val,
                          const int* __restrict__ csr_cnt,
                          float* __restrict__ enc_out) {
    const int tid = threadIdx.x;            // 256 = 4 waves, 1 wave per row
    const int lane = tid & 63;
    const int i = blockIdx.x * 4 + (tid >> 6);   // 375*4 == 1500 exact

    float hv = 0.f;
    if (lane < GOUT) {
        #pragma unroll 4
        for (int c = 0; c < IN; ++c)
            hv = fmaf(enc[(size_t)i * IN + c], W[c * GOUT + lane], hv);
    }
    float hi[GOUT];
    #pragma unroll
    for (int c = 0; c < GOUT; ++c) hi[c] = __shfl(hv, c, 64);
    float fsrc = 0.f;
    #pragma unroll
    for (int c = 0; c < GOUT; ++c) fsrc = fmaf(hi[c], avec[c], fsrc);

    const int cnt = csr_cnt[i];
    float den = 0.f;
    float num[GOUT] = {};
    for (int e = lane; e < cnt; e += 64) {
        int j = csr_idx[(size_t)i * CAP + e];
        float a = csr_val[(size_t)i * CAP + e];
        float hj[GOUT] = {};
        #pragma unroll
        for (int c4 = 0; c4 < IN / 4; ++c4) {
            float4 e4 = *(const float4*)(enc + (size_t)j * IN + 4 * c4);
            const float* ep = (const float*)&e4;
            #pragma unroll
            for (int c = 0; c < 4; ++c)
                #pragma unroll
                for (int k = 0; k < GOUT; ++k)
                    hj[k] = fmaf(ep[c], W[(4 * c4 + c) * GOUT + k], hj[k]);
        }
        float fd = 0.f;
        #pragma unroll
        for (int k = 0; k < GOUT; ++k) fd = fmaf(hj[k], avec[GOUT + k], fd);
        float ev = fsrc + fd;
        ev = (ev > 0.f) ? ev : 0.2f * ev;
        ev *= a;
        float p = __expf(ev);
        den += p;
        #pragma unroll
        for (int k = 0; k < GOUT; ++k) num[k] = fmaf(p, hj[k], num[k]);
    }
    #pragma unroll
    for (int off = 32; off > 0; off >>= 1) {
        den += __shfl_xor(den, off, 64);
        #pragma unroll
        for (int k = 0; k < GOUT; ++k) num[k] += __shfl_xor(num[k], off, 64);
    }
    if (lane < GOUT) {
        float v = num[lane] / den;
        enc_out[(size_t)i * GOUT + lane] = (v > 0.f) ? v : (__expf(v) - 1.f);
    }
}

// ---------------------------------------------------------------------------
// Fused UV + pair-MLP.
// Tile 96(i) x 48(j), grid 16x32 = 512 blocks = EXACTLY 2 blocks/CU.
// LDS = (96+48)*68*4 = 39.2 KB -> 2 resident -> 8 waves/CU (2/SIMD) for
// latency hiding (round-4 failure mode: 1 wave/SIMD, VALUBusy 42%).
// Per-thread 6x3 register tile; packed math forced via elementwise builtins;
// w16/fc2w read with wave-uniform address -> s_load (SMEM pipe, no LDS).
// ---------------------------------------------------------------------------
#define MTI 96
#define MTJ 48
#define KS 64
#define KSTR 68   // 64 + 4 pad; rows 16B-aligned; U: 4 addrs/wave, V: 2-way -> free

__global__ __launch_bounds__(256, 2) void mlp_kernel(
        const float* __restrict__ enc,
        const float* __restrict__ dist,
        const float* __restrict__ fc1w,   // 17 x 128
        const float* __restrict__ fc1b,   // 128
        const float* __restrict__ fc2w,   // 128
        const float* __restrict__ fc2b,   // 1
        float* __restrict__ out) {
    __shared__ float Us[MTI * KSTR];
    __shared__ float Vs[MTJ * KSTR];

    const int tid = threadIdx.x;
    const int i0 = blockIdx.y * MTI;
    const int j0 = blockIdx.x * MTJ;
    const int tx = tid & 15;
    const int ty = tid >> 4;

    const float* w16g = fc1w + 2 * GOUT * HID;

    // distance tile: 18 scalars, persist in registers across both k-phases
    int irow[6], jcol[3];
    float d[6][3];
    #pragma unroll
    for (int ii = 0; ii < 6; ++ii) irow[ii] = i0 + ty + 16 * ii;
    #pragma unroll
    for (int jj = 0; jj < 3; ++jj) jcol[jj] = j0 + tx + 16 * jj;
    #pragma unroll
    for (int ii = 0; ii < 6; ++ii) {
        int ic = irow[ii] < NN ? irow[ii] : NN - 1;
        #pragma unroll
        for (int jj = 0; jj < 3; ++jj) {
            int jc = jcol[jj] < NN ? jcol[jj] : NN - 1;
            d[ii][jj] = dist[(size_t)ic * NN + jc];
        }
    }

    v2f acc[6][3] = {};

    #pragma unroll
    for (int ph = 0; ph < 2; ++ph) {
        const int k0 = ph * KS;
        if (ph) __syncthreads();
        // stage U (96x16 float4) then V (48x16 float4): 2304 units, 9/thread
        for (int u = tid; u < (MTI + MTJ) * 16; u += 256) {
            const int isU = (u < MTI * 16);
            const int q = isU ? u : u - MTI * 16;
            const int r = q >> 4;
            const int k4 = k0 + ((q & 15) << 2);
            int g = (isU ? i0 : j0) + r;
            if (g >= NN) g = NN - 1;
            float4 acc4;
            if (isU) acc4 = *(const float4*)(fc1b + k4);
            else acc4 = make_float4(0.f, 0.f, 0.f, 0.f);
            const float* wbase = fc1w + (isU ? 0 : GOUT) * HID + k4;
            const float* ep = enc + (size_t)g * GOUT;
            #pragma unroll
            for (int c = 0; c < GOUT; ++c) {
                float e = ep[c];
                float4 w4 = *(const float4*)(wbase + c * HID);
                acc4.x = fmaf(e, w4.x, acc4.x);
                acc4.y = fmaf(e, w4.y, acc4.y);
                acc4.z = fmaf(e, w4.z, acc4.z);
                acc4.w = fmaf(e, w4.w, acc4.w);
            }
            *(float4*)((isU ? Us : Vs) + r * KSTR + (k4 - k0)) = acc4;
        }
        __syncthreads();

        for (int k4 = 0; k4 < KS; k4 += 4) {
            float4 u4[6], v4[3];
            #pragma unroll
            for (int ii = 0; ii < 6; ++ii)
                u4[ii] = *(const float4*)(Us + (ty + 16 * ii) * KSTR + k4);
            #pragma unroll
            for (int jj = 0; jj < 3; ++jj)
                v4[jj] = *(const float4*)(Vs + (tx + 16 * jj) * KSTR + k4);
            // wave-uniform k -> scalar (SMEM) loads, no LDS/VALU cost
            v2f wlo = *(const v2f*)(w16g + k0 + k4);
            v2f whi = *(const v2f*)(w16g + k0 + k4 + 2);
            v2f flo = *(const v2f*)(fc2w + k0 + k4);
            v2f fhi = *(const v2f*)(fc2w + k0 + k4 + 2);
            #pragma unroll
            for (int h = 0; h < 2; ++h) {
                v2f w2 = h ? whi : wlo;
                v2f f2 = h ? fhi : flo;
                #pragma unroll
                for (int ii = 0; ii < 6; ++ii) {
                    v2f u2 = ((const v2f*)&u4[ii])[h];
                    #pragma unroll
                    for (int jj = 0; jj < 3; ++jj) {
                        v2f tt = u2 + ((const v2f*)&v4[jj])[h];
                        tt = __builtin_elementwise_fma((v2f)d[ii][jj], w2, tt);
                        tt = __builtin_elementwise_max(tt, (v2f)0.f);
                        acc[ii][jj] = __builtin_elementwise_fma(tt, f2, acc[ii][jj]);
                    }
                }
            }
        }
    }

    const float b2 = fc2b[0];
    #pragma unroll
    for (int ii = 0; ii < 6; ++ii) {
        if (irow[ii] >= NN) continue;
        #pragma unroll
        for (int jj = 0; jj < 3; ++jj) {
            if (jcol[jj] >= NN) continue;
            out[(size_t)irow[ii] * NN + jcol[jj]] = acc[ii][jj].x + acc[ii][jj].y + b2;
        }
    }
}

// ---------------------------------------------------------------------------
extern "C" void kernel_launch(void* const* d_in, const int* in_sizes, int n_in,
                              void* d_out, int out_size, void* d_ws, size_t ws_size,
                              hipStream_t stream) {
    const float* geo  = (const float*)d_in[0];
    const float* sem  = (const float*)d_in[1];
    const float* feat = (const float*)d_in[2];
    // d_in[3] = region_pairs: full meshgrid -> row-major (i,j); unused
    const float* dist = (const float*)d_in[4];
    const float* W0   = (const float*)d_in[5];
    const float* W1   = (const float*)d_in[6];
    const float* W2   = (const float*)d_in[7];
    const float* a0   = (const float*)d_in[8];
    const float* a1   = (const float*)d_in[9];
    const float* a2   = (const float*)d_in[10];
    const float* fc1w = (const float*)d_in[11];
    const float* fc1b = (const float*)d_in[12];
    const float* fc2w = (const float*)d_in[13];
    const float* fc2b = (const float*)d_in[14];
    float* out = (float*)d_out;

    // workspace layout (~2.5 MB)
    char* ws = (char*)d_ws;
    int*   csr_idx = (int*)ws;                         ws += sizeof(int) * NN * CAP;
    float* csr_val = (float*)ws;                       ws += sizeof(float) * NN * CAP;
    int*   csr_cnt = (int*)ws;                         ws += sizeof(int) * NN;
    float* encA    = (float*)ws;                       ws += sizeof(float) * NN * GOUT;
    float* encB    = (float*)ws;

    gat_first<<<NN, 256, 0, stream>>>(geo, sem, feat, W0, a0,
                                      csr_idx, csr_val, csr_cnt, encA);
    gat_layer<GOUT><<<NN / 4, 256, 0, stream>>>(encA, W1, a1, csr_idx, csr_val, csr_cnt, encB);
    gat_layer<GOUT><<<NN / 4, 256, 0, stream>>>(encB, W2, a2, csr_idx, csr_val, csr_cnt, encA);

    dim3 mg(32, 16);  // x: j tiles of 48 (32*48=1536), y: i tiles of 96 (16*96=1536)
    mlp_kernel<<<mg, 256, 0, stream>>>(encA, dist, fc1w, fc1b, fc2w, fc2b, out);
}